// Round 4
// baseline (2395.305 us; speedup 1.0000x reference)
//
#include <hip/hip_runtime.h>

// LNN R12: purity hammer. Math is BIT-IDENTICAL to R10/R11 (absmax 3584 < 5366
// proven on HW). R10/R11 failed only the launch-vs-graph tripwire with
// reproducible, context-dependent divergence -- the signature of a read of
// persistent device state (LDS survives across launches on a CU). Defense:
//   1. Pre-zero ALL 131072 B of LDS before staging (+1 barrier): every LDS
//      byte becomes a pure function of kernel inputs, independent of any
//      staging-coverage subtlety.
//   2. Zero-init every macro-filled temporary (U8 unions, fragment regs):
//      no register/scratch slot carries prior-context garbage.
// Everything else unchanged:
// - Software-RNE bf16 3-split (exact: 8+8+8 bits, Sterbenz residuals).
// - 8-pass split product (only ll ~2^-32 dropped).
// - LDS 131072 B: fwd-H (32K) + fwd-ML pair plane (64K, dword = m|l<<16,
//   half-swap XOR keeps fwd b128 reads conflict-free) + col-H (32K).
//   col m/l gathered as 8x b32 from fwd-ML (~4-way conflict, acceptable).
// - Wave = 16 rows; lane l owns row l&15, channels {16mt + 4(l>>4) + j};
//   k-slot map (g, 4u+j) <-> 32t+16u+4g+j applied identically to A and B.

using bf16x8 = __attribute__((ext_vector_type(8))) short;
using f32x4  = __attribute__((ext_vector_type(4))) float;

#define NGRID    256
#define NTHREADS 512          // 8 waves; 16 rows/wave/iter
#define NITERS   8            // 256 * 8 * 16 * 8 = 262144 rows
#define FWDH  0
#define FWDML 32768
#define COLH  98304
#define LDS_BYTES 131072

__device__ __forceinline__ unsigned bf16b(float x) {           // RNE f32->bf16 bits
    unsigned u = __float_as_uint(x);
    return (u + 0x7fffu + ((u >> 16) & 1u)) >> 16;
}

// exact 3-way bf16 split of a pair, packed (a in lo16, b in hi16 per level)
__device__ __forceinline__ void sp3(float a, float b, unsigned& h, unsigned& m, unsigned& l) {
    const unsigned ha = bf16b(a), hb = bf16b(b);
    h = ha | (hb << 16);
    const float ra = a - __uint_as_float(ha << 16);
    const float rb = b - __uint_as_float(hb << 16);
    const unsigned ma = bf16b(ra), mb = bf16b(rb);
    m = ma | (mb << 16);
    const float qa = ra - __uint_as_float(ma << 16);
    const float qb = rb - __uint_as_float(mb << 16);
    l = bf16b(qa) | (bf16b(qb) << 16);     // exact: residual fits 8 bits
}

__device__ __forceinline__ float red4(float x) {   // sum over the 4 lanes of one row
    x += __shfl_xor(x, 16, 64);
    x += __shfl_xor(x, 32, 64);
    return x;
}

union U8 { unsigned u[4]; bf16x8 v; };

#define MM(A, B, C) (C) = __builtin_amdgcn_mfma_f32_16x16x32_bf16((A), (B), (C), 0, 0, 0)
// 8-pass split product: only ll (~2^-32) dropped
#define PASS8(Ah, Am, Al, Bh, Bm, Bl, C) do { \
    MM(Ah, Bh, C); MM(Ah, Bm, C); MM(Am, Bh, C); MM(Am, Bm, C); \
    MM(Ah, Bl, C); MM(Al, Bh, C); MM(Am, Bl, C); MM(Al, Bm, C); } while (0)

// pack B-fragment (k-step t) from value array arr[8][4] (tiles 2t, 2t+1)
#define PACKB3(arr, t, Bh, Bm, Bl) do { U8 H_ = {}, M_ = {}, L_ = {}; \
    sp3(arr[2*(t)][0],   arr[2*(t)][1],   H_.u[0], M_.u[0], L_.u[0]); \
    sp3(arr[2*(t)][2],   arr[2*(t)][3],   H_.u[1], M_.u[1], L_.u[1]); \
    sp3(arr[2*(t)+1][0], arr[2*(t)+1][1], H_.u[2], M_.u[2], L_.u[2]); \
    sp3(arr[2*(t)+1][2], arr[2*(t)+1][3], H_.u[3], M_.u[3], L_.u[3]); \
    (Bh) = H_.v; (Bm) = M_.v; (Bl) = L_.v; } while (0)

// fwd A-fragment: H via b128; M,L unpacked from the ML pair-plane (2x b128)
#define LOADFWD(mt, t, Ah, Am, Al) do { \
    const int fo_ = ((mt) * 4 + (t)); \
    (Ah) = *(const bf16x8*)(aH + fo_ * 1024); \
    const uint4 dA_ = *(const uint4*)(mlr0 + fo_ * 2048); /* elems 0-3 (m,l) pairs */ \
    const uint4 dB_ = *(const uint4*)(mlr1 + fo_ * 2048); /* elems 4-7 */ \
    U8 M_ = {}, L_ = {}; \
    M_.u[0] = (dA_.x & 0xffffu) | (dA_.y << 16); \
    M_.u[1] = (dA_.z & 0xffffu) | (dA_.w << 16); \
    M_.u[2] = (dB_.x & 0xffffu) | (dB_.y << 16); \
    M_.u[3] = (dB_.z & 0xffffu) | (dB_.w << 16); \
    L_.u[0] = (dA_.x >> 16) | (dA_.y & 0xffff0000u); \
    L_.u[1] = (dA_.z >> 16) | (dA_.w & 0xffff0000u); \
    L_.u[2] = (dB_.x >> 16) | (dB_.y & 0xffff0000u); \
    L_.u[3] = (dB_.z >> 16) | (dB_.w & 0xffff0000u); \
    (Am) = M_.v; (Al) = L_.v; } while (0)

// col (transpose) A-fragment: H via b128 from col-H plane; M,L gathered as
// 8x b32 from the fwd-ML plane (dword = m|l<<16 for W2[r][c2], r=32t+16u+4gq+j)
#define LOADCOL(mt, t, Ah, Am, Al) do { \
    (Ah) = *(const bf16x8*)(cH + ((mt) * 4 + (t)) * 1024); \
    const char* q_ = colML + ((mt) >> 1) * 2048 + (t) * 16384; \
    const unsigned x0_ = (unsigned)(((mt) & 1) << 4); \
    const unsigned w0_ = *(const unsigned*)(q_ +           0 + x0_); \
    const unsigned w1_ = *(const unsigned*)(q_ +         128 + (x0_ ^ 16u)); \
    const unsigned w2_ = *(const unsigned*)(q_ +         256 + x0_); \
    const unsigned w3_ = *(const unsigned*)(q_ +         384 + (x0_ ^ 16u)); \
    const unsigned w4_ = *(const unsigned*)(q_ + 8192 +    0 + x0_); \
    const unsigned w5_ = *(const unsigned*)(q_ + 8192 +  128 + (x0_ ^ 16u)); \
    const unsigned w6_ = *(const unsigned*)(q_ + 8192 +  256 + x0_); \
    const unsigned w7_ = *(const unsigned*)(q_ + 8192 +  384 + (x0_ ^ 16u)); \
    U8 M_ = {}, L_ = {}; \
    M_.u[0] = (w0_ & 0xffffu) | (w1_ << 16); \
    M_.u[1] = (w2_ & 0xffffu) | (w3_ << 16); \
    M_.u[2] = (w4_ & 0xffffu) | (w5_ << 16); \
    M_.u[3] = (w6_ & 0xffffu) | (w7_ << 16); \
    L_.u[0] = (w0_ >> 16) | (w1_ & 0xffff0000u); \
    L_.u[1] = (w2_ >> 16) | (w3_ & 0xffff0000u); \
    L_.u[2] = (w4_ >> 16) | (w5_ & 0xffff0000u); \
    L_.u[3] = (w6_ >> 16) | (w7_ & 0xffff0000u); \
    (Am) = M_.v; (Al) = L_.v; } while (0)

extern "C" __global__ __launch_bounds__(NTHREADS, 2)
void lnn_kernel(const float* __restrict__ gx, const float* __restrict__ gW1,
                const float* __restrict__ gb1, const float* __restrict__ gW2,
                const float* __restrict__ gb2, const float* __restrict__ gW3,
                float* __restrict__ gout)
{
    extern __shared__ __align__(16) char lds[];
    const int tid = threadIdx.x;

    // ---- purity hammer: LDS content = f(inputs) only, never prior-launch state
    for (int e4 = tid; e4 < (LDS_BYTES / 4); e4 += NTHREADS)
        ((unsigned*)lds)[e4] = 0u;
    __syncthreads();

    // ---- one-time: build W2 planes (exact software-RNE 3-split) ----
    for (int e = tid; e < 16384; e += NTHREADS) {
        const int r = e >> 7, c = e & 127;          // W2[r][c]
        const float w = gW2[e];
        const unsigned hb = bf16b(w);
        const float r1f = w - __uint_as_float(hb << 16);
        const unsigned mb = bf16b(r1f);
        const float r2f = r1f - __uint_as_float(mb << 16);
        const unsigned lb = bf16b(r2f);             // exact: w == h+m+l
        // fwd planes: A[m=r][k=c]; slot s=(r&15)*4+((c>>2)&3); elem e=((c>>4)&1)*4+(c&3)
        const int fragF = (r >> 4) * 4 + (c >> 5);
        const int sF    = (r & 15) * 4 + ((c >> 2) & 3);
        const int eF    = ((c >> 4) & 1) * 4 + (c & 3);
        *(unsigned short*)(lds + FWDH + fragF * 1024 + sF * 16 + eF * 2) = (unsigned short)hb;
        // ML pair-plane: 32B slots, half-swap XOR on (row&1) => conflict-free b128 reads
        *(unsigned*)(lds + FWDML + fragF * 2048 + sF * 32
                     + ((((eF >> 2) ^ ((sF >> 2) & 1)) << 4)) + (eF & 3) * 4)
            = mb | (lb << 16);
        // col-H plane: A'[m'=c][k'=r]
        const int fragC = (c >> 4) * 4 + (r >> 5);
        const int sC    = (c & 15) * 4 + ((r >> 2) & 3);
        const int eC    = ((r >> 4) & 1) * 4 + (r & 3);
        *(unsigned short*)(lds + COLH + fragC * 1024 + sC * 16 + eC * 2) = (unsigned short)hb;
    }
    __syncthreads();   // planes read-only from here; no further block syncs

    const int l  = tid & 63;
    const int wv = tid >> 6;
    const int n  = l & 15;        // row within wave tile
    const int gq = l >> 4;        // lane group (k-slice / channel sub-block)
    const int s  = n * 4 + gq;    // fragment lane-slot

    const char* aH    = lds + FWDH  + s * 16;
    const char* mlr0  = lds + FWDML + s * 32 + ((n & 1) << 4);        // elems 0-3
    const char* mlr1  = lds + FWDML + s * 32 + (((n & 1) ^ 1) << 4);  // elems 4-7
    const char* cH    = lds + COLH  + s * 16;
    const char* colML = lds + FWDML + gq * 512 + ((n >> 2) & 3) * 32 + (n & 3) * 4;

    const float4* gW14 = (const float4*)gW1;

#pragma unroll 1
    for (int it = 0; it < NITERS; ++it) {
        const int grow = blockIdx.x * (NITERS * 8 * 16) + wv * (NITERS * 16) + it * 16 + n;
        const float4 xr = ((const float4*)gx)[grow];

        // ---- P0: layer 1  p = softmax(W1 x + b1); pi2 = p.t2, pi3 = p.t3
        f32x4 p[8];
        float se = 0.f, s2a = 0.f, s3a = 0.f;
#pragma unroll
        for (int mt = 0; mt < 8; ++mt) {
#pragma unroll
            for (int j = 0; j < 4; ++j) {
                const int c = mt * 16 + gq * 4 + j;
                const float4 w1 = gW14[c];
                const float z1 = fmaf(w1.x, xr.x, fmaf(w1.y, xr.y,
                                  fmaf(w1.z, xr.z, fmaf(w1.w, xr.w, gb1[c]))));
                const float e1 = __expf(z1);
                p[mt][j] = e1;
                se += e1;
                s2a = fmaf(e1, w1.z, s2a);
                s3a = fmaf(e1, w1.w, s3a);
            }
        }
        se = red4(se); s2a = red4(s2a); s3a = red4(s3a);
        const float rs1 = 1.0f / se;
        const float pi2 = s2a * rs1, pi3 = s3a * rs1;
#pragma unroll
        for (int mt = 0; mt < 8; ++mt)
#pragma unroll
            for (int j = 0; j < 4; ++j) p[mt][j] *= rs1;

        // ---- Sweep 1: z = W2 p ; zd2 = W2 pd2 ; zd3 = W2 pd3
        f32x4 az[8] = {}, a2[8] = {}, a3[8] = {};
#pragma unroll
        for (int t = 0; t < 4; ++t) {
            float d2v[8], d3v[8];
#pragma unroll
            for (int u = 0; u < 2; ++u)
#pragma unroll
                for (int j = 0; j < 4; ++j) {
                    const int c = (2 * t + u) * 16 + gq * 4 + j;
                    const float4 w1 = gW14[c];
                    const float pc = p[2 * t + u][j];
                    d2v[u * 4 + j] = pc * (w1.z - pi2);
                    d3v[u * 4 + j] = pc * (w1.w - pi3);
                }
            bf16x8 Bph = {}, Bpm = {}, Bpl = {}; PACKB3(p, t, Bph, Bpm, Bpl);
            U8 H2_ = {}, M2_ = {}, L2_ = {}, H3_ = {}, M3_ = {}, L3_ = {};
            sp3(d2v[0], d2v[1], H2_.u[0], M2_.u[0], L2_.u[0]);
            sp3(d2v[2], d2v[3], H2_.u[1], M2_.u[1], L2_.u[1]);
            sp3(d2v[4], d2v[5], H2_.u[2], M2_.u[2], L2_.u[2]);
            sp3(d2v[6], d2v[7], H2_.u[3], M2_.u[3], L2_.u[3]);
            sp3(d3v[0], d3v[1], H3_.u[0], M3_.u[0], L3_.u[0]);
            sp3(d3v[2], d3v[3], H3_.u[1], M3_.u[1], L3_.u[1]);
            sp3(d3v[4], d3v[5], H3_.u[2], M3_.u[2], L3_.u[2]);
            sp3(d3v[6], d3v[7], H3_.u[3], M3_.u[3], L3_.u[3]);
            const bf16x8 B2h = H2_.v, B2m = M2_.v, B2l = L2_.v;
            const bf16x8 B3h = H3_.v, B3m = M3_.v, B3l = L3_.v;
#pragma unroll
            for (int mt = 0; mt < 8; ++mt) {
                bf16x8 Ah = {}, Am = {}, Al = {};
                LOADFWD(mt, t, Ah, Am, Al);
                PASS8(Ah, Am, Al, Bph, Bpm, Bpl, az[mt]);
                PASS8(Ah, Am, Al, B2h, B2m, B2l, a2[mt]);
                PASS8(Ah, Am, Al, B3h, B3m, B3l, a3[mt]);
            }
        }

        // ---- P3: softmax-2 chain; az->u, a2->ud2, a3->ud3 (in place)
        float s2 = 0.f, sw3 = 0.f, s2d2 = 0.f, s2d3 = 0.f, sw3d2 = 0.f, sw3d3 = 0.f;
#pragma unroll
        for (int mt = 0; mt < 8; ++mt)
#pragma unroll
            for (int j = 0; j < 4; ++j) {
                const int c = mt * 16 + gq * 4 + j;
                const float z  = az[mt][j] + gb2[c];
                const float e2 = __expf(z);
                const float w3c = gW3[c];
                az[mt][j] = e2;
                s2 += e2;
                sw3   = fmaf(w3c, e2, sw3);
                s2d2  = fmaf(e2, a2[mt][j], s2d2);
                s2d3  = fmaf(e2, a3[mt][j], s2d3);
                sw3d2 = fmaf(w3c * e2, a2[mt][j], sw3d2);
                sw3d3 = fmaf(w3c * e2, a3[mt][j], sw3d3);
            }
        s2 = red4(s2); sw3 = red4(sw3); s2d2 = red4(s2d2); s2d3 = red4(s2d3);
        sw3d2 = red4(sw3d2); sw3d3 = red4(sw3d3);
        const float rs2 = 1.0f / s2;
        const float sw  = sw3 * rs2;                       // W3.q
        const float sg2 = s2d2 * rs2, sg3 = s2d3 * rs2;    // q.zd_T
        const float sd2 = fmaf(-sg2, sw, sw3d2 * rs2);     // W3.qd2
        const float sd3 = fmaf(-sg3, sw, sw3d3 * rs2);
#pragma unroll
        for (int mt = 0; mt < 8; ++mt)
#pragma unroll
            for (int j = 0; j < 4; ++j) {
                const int c = mt * 16 + gq * 4 + j;
                const float w3c = gW3[c];
                const float e2 = az[mt][j];
                const float qq = e2 * rs2;
                const float uu = qq * (w3c - sw);
                const float zd2c = a2[mt][j], zd3c = a3[mt][j];
                az[mt][j] = uu;                                    // u
                a2[mt][j] = fmaf(uu, zd2c - sg2, -(sd2 * qq));     // ud2
                a3[mt][j] = fmaf(uu, zd3c - sg3, -(sd3 * qq));     // ud3
            }

        // ---- Sweep 2a: v = W2^T u
        f32x4 av[8] = {};
#pragma unroll
        for (int t = 0; t < 4; ++t) {
            bf16x8 Buh = {}, Bum = {}, Bul = {}; PACKB3(az, t, Buh, Bum, Bul);
#pragma unroll
            for (int mt = 0; mt < 8; ++mt) {
                bf16x8 Ah = {}, Am = {}, Al = {};
                LOADCOL(mt, t, Ah, Am, Al);
                PASS8(Ah, Am, Al, Buh, Bum, Bul, av[mt]);
            }
        }
        // ---- Sweep 2b: vd2 = W2^T ud2 ; vd3 = W2^T ud3
        f32x4 ad2[8] = {}, ad3[8] = {};
#pragma unroll
        for (int t = 0; t < 4; ++t) {
            bf16x8 B2h = {}, B2m = {}, B2l = {}; PACKB3(a2, t, B2h, B2m, B2l);
            bf16x8 B3h = {}, B3m = {}, B3l = {}; PACKB3(a3, t, B3h, B3m, B3l);
#pragma unroll
            for (int mt = 0; mt < 8; ++mt) {
                bf16x8 Ah = {}, Am = {}, Al = {};
                LOADCOL(mt, t, Ah, Am, Al);
                PASS8(Ah, Am, Al, B2h, B2m, B2l, ad2[mt]);
                PASS8(Ah, Am, Al, B3h, B3m, B3l, ad3[mt]);
            }
        }

        // ---- P5: recompute p (bit-identical); reductions; h's; fp64 solve
        f32x4 pr[8];
        float pv = 0.f, dv2 = 0.f, dv3 = 0.f;
#pragma unroll
        for (int mt = 0; mt < 8; ++mt)
#pragma unroll
            for (int j = 0; j < 4; ++j) {
                const int c = mt * 16 + gq * 4 + j;
                const float4 w1 = gW14[c];
                const float z1 = fmaf(w1.x, xr.x, fmaf(w1.y, xr.y,
                                  fmaf(w1.z, xr.z, fmaf(w1.w, xr.w, gb1[c]))));
                const float pc = __expf(z1) * rs1;
                pr[mt][j] = pc;
                const float pd2c = pc * (w1.z - pi2);
                const float pd3c = pc * (w1.w - pi3);
                pv  = fmaf(pc, av[mt][j], pv);
                dv2 = fmaf(pd2c, av[mt][j], fmaf(pc, ad2[mt][j], dv2));
                dv3 = fmaf(pd3c, av[mt][j], fmaf(pc, ad3[mt][j], dv3));
            }
        pv = red4(pv); dv2 = red4(dv2); dv3 = red4(dv3);

        float h20 = 0.f, h21 = 0.f, h22 = 0.f, h23 = 0.f;
        float h30 = 0.f, h31 = 0.f, h32 = 0.f, h33 = 0.f, g0a = 0.f;
#pragma unroll
        for (int mt = 0; mt < 8; ++mt)
#pragma unroll
            for (int j = 0; j < 4; ++j) {
                const int c = mt * 16 + gq * 4 + j;
                const float4 w1 = gW14[c];
                const float pc = pr[mt][j];
                const float pd2c = pc * (w1.z - pi2);
                const float pd3c = pc * (w1.w - pi3);
                const float vm = av[mt][j] - pv;
                const float gd2 = fmaf(pd2c, vm, pc * (ad2[mt][j] - dv2));
                const float gd3 = fmaf(pd3c, vm, pc * (ad3[mt][j] - dv3));
                h20 = fmaf(w1.x, gd2, h20); h21 = fmaf(w1.y, gd2, h21);
                h22 = fmaf(w1.z, gd2, h22); h23 = fmaf(w1.w, gd2, h23);
                h30 = fmaf(w1.x, gd3, h30); h31 = fmaf(w1.y, gd3, h31);
                h32 = fmaf(w1.z, gd3, h32); h33 = fmaf(w1.w, gd3, h33);
                g0a = fmaf(w1.x, pc * vm, g0a);
            }
        h20 = red4(h20); h21 = red4(h21); h22 = red4(h22); h23 = red4(h23);
        h30 = red4(h30); h31 = red4(h31); h32 = red4(h32); h33 = red4(h33);
        g0a = red4(g0a);

        // ---- 2x2 solve in fp64 (identical to R8)
        const double rhs0 = (double)g0a - ((double)h20 * (double)xr.z + (double)h21 * (double)xr.w);
        const double rhs1 = (double)g0a - ((double)h30 * (double)xr.z + (double)h31 * (double)xr.w);
        const double a_ = (double)h22, b_ = (double)h32, c_ = (double)h23, d_ = (double)h33;
        const double det = a_ * d_ - b_ * c_;
        const float t0 = (float)((d_ * rhs0 - b_ * rhs1) / det);
        const float t1 = (float)((a_ * rhs1 - c_ * rhs0) / det);
        if (gq == 0) {
            ((float4*)gout)[grow] = make_float4(xr.z, xr.w, t0, t1);
        }
    }
}

extern "C" void kernel_launch(void* const* d_in, const int* in_sizes, int n_in,
                              void* d_out, int out_size, void* d_ws, size_t ws_size,
                              hipStream_t stream)
{
    const float* gx  = (const float*)d_in[0];
    const float* gW1 = (const float*)d_in[1];
    const float* gb1 = (const float*)d_in[2];
    const float* gW2 = (const float*)d_in[3];
    const float* gb2 = (const float*)d_in[4];
    const float* gW3 = (const float*)d_in[5];
    float* gout = (float*)d_out;

    (void)hipFuncSetAttribute((const void*)lnn_kernel,
                              hipFuncAttributeMaxDynamicSharedMemorySize, LDS_BYTES);
    lnn_kernel<<<NGRID, NTHREADS, LDS_BYTES, stream>>>(gx, gW1, gb1, gW2, gb2, gW3, gout);
}

// Round 5
// 2383.879 us; speedup vs baseline: 1.0048x; 1.0048x over previous
//
#include <hip/hip_runtime.h>

// LNN R13: R12 (passed, absmax 3584) with the spill catastrophe fixed.
// R12 counters: FETCH 3.9GB / WRITE 2.2GB (~6GB scratch traffic), VGPR=128,
// MfmaUtil 7%, VALUBusy 8% -- allocator targeted 4 waves/EU (128-VGPR budget)
// and spilled ~100 dwords hot. Live-set peak is ~212 dwords; fits 256.
// Fix: amdgpu_waves_per_eu(2,2) pins occupancy at 2 waves/EU (= 1 block/CU,
// which the 128KB LDS already forces) so the allocator gets 256 VGPRs.
// Device math BIT-IDENTICAL to R12 (proven absmax + tripwire-pass):
// - LDS pre-zero purity hammer (fixed the launch-vs-graph tripwire).
// - Software-RNE bf16 3-split (exact), 8-pass split product (only ll dropped).
// - LDS 131072 B: fwd-H (32K) + fwd-ML pair plane (64K) + col-H (32K).
// - Wave = 16 rows; lane l owns row l&15, channels {16mt + 4(l>>4) + j}.

using bf16x8 = __attribute__((ext_vector_type(8))) short;
using f32x4  = __attribute__((ext_vector_type(4))) float;

#define NGRID    256
#define NTHREADS 512          // 8 waves; 16 rows/wave/iter
#define NITERS   8            // 256 * 8 * 16 * 8 = 262144 rows
#define FWDH  0
#define FWDML 32768
#define COLH  98304
#define LDS_BYTES 131072

__device__ __forceinline__ unsigned bf16b(float x) {           // RNE f32->bf16 bits
    unsigned u = __float_as_uint(x);
    return (u + 0x7fffu + ((u >> 16) & 1u)) >> 16;
}

// exact 3-way bf16 split of a pair, packed (a in lo16, b in hi16 per level)
__device__ __forceinline__ void sp3(float a, float b, unsigned& h, unsigned& m, unsigned& l) {
    const unsigned ha = bf16b(a), hb = bf16b(b);
    h = ha | (hb << 16);
    const float ra = a - __uint_as_float(ha << 16);
    const float rb = b - __uint_as_float(hb << 16);
    const unsigned ma = bf16b(ra), mb = bf16b(rb);
    m = ma | (mb << 16);
    const float qa = ra - __uint_as_float(ma << 16);
    const float qb = rb - __uint_as_float(mb << 16);
    l = bf16b(qa) | (bf16b(qb) << 16);     // exact: residual fits 8 bits
}

__device__ __forceinline__ float red4(float x) {   // sum over the 4 lanes of one row
    x += __shfl_xor(x, 16, 64);
    x += __shfl_xor(x, 32, 64);
    return x;
}

union U8 { unsigned u[4]; bf16x8 v; };

#define MM(A, B, C) (C) = __builtin_amdgcn_mfma_f32_16x16x32_bf16((A), (B), (C), 0, 0, 0)
// 8-pass split product: only ll (~2^-32) dropped
#define PASS8(Ah, Am, Al, Bh, Bm, Bl, C) do { \
    MM(Ah, Bh, C); MM(Ah, Bm, C); MM(Am, Bh, C); MM(Am, Bm, C); \
    MM(Ah, Bl, C); MM(Al, Bh, C); MM(Am, Bl, C); MM(Al, Bm, C); } while (0)

// pack B-fragment (k-step t) from value array arr[8][4] (tiles 2t, 2t+1)
#define PACKB3(arr, t, Bh, Bm, Bl) do { U8 H_ = {}, M_ = {}, L_ = {}; \
    sp3(arr[2*(t)][0],   arr[2*(t)][1],   H_.u[0], M_.u[0], L_.u[0]); \
    sp3(arr[2*(t)][2],   arr[2*(t)][3],   H_.u[1], M_.u[1], L_.u[1]); \
    sp3(arr[2*(t)+1][0], arr[2*(t)+1][1], H_.u[2], M_.u[2], L_.u[2]); \
    sp3(arr[2*(t)+1][2], arr[2*(t)+1][3], H_.u[3], M_.u[3], L_.u[3]); \
    (Bh) = H_.v; (Bm) = M_.v; (Bl) = L_.v; } while (0)

// fwd A-fragment: H via b128; M,L unpacked from the ML pair-plane (2x b128)
#define LOADFWD(mt, t, Ah, Am, Al) do { \
    const int fo_ = ((mt) * 4 + (t)); \
    (Ah) = *(const bf16x8*)(aH + fo_ * 1024); \
    const uint4 dA_ = *(const uint4*)(mlr0 + fo_ * 2048); /* elems 0-3 (m,l) pairs */ \
    const uint4 dB_ = *(const uint4*)(mlr1 + fo_ * 2048); /* elems 4-7 */ \
    U8 M_ = {}, L_ = {}; \
    M_.u[0] = (dA_.x & 0xffffu) | (dA_.y << 16); \
    M_.u[1] = (dA_.z & 0xffffu) | (dA_.w << 16); \
    M_.u[2] = (dB_.x & 0xffffu) | (dB_.y << 16); \
    M_.u[3] = (dB_.z & 0xffffu) | (dB_.w << 16); \
    L_.u[0] = (dA_.x >> 16) | (dA_.y & 0xffff0000u); \
    L_.u[1] = (dA_.z >> 16) | (dA_.w & 0xffff0000u); \
    L_.u[2] = (dB_.x >> 16) | (dB_.y & 0xffff0000u); \
    L_.u[3] = (dB_.z >> 16) | (dB_.w & 0xffff0000u); \
    (Am) = M_.v; (Al) = L_.v; } while (0)

// col (transpose) A-fragment: H via b128 from col-H plane; M,L gathered as
// 8x b32 from the fwd-ML plane (dword = m|l<<16 for W2[r][c2], r=32t+16u+4gq+j)
#define LOADCOL(mt, t, Ah, Am, Al) do { \
    (Ah) = *(const bf16x8*)(cH + ((mt) * 4 + (t)) * 1024); \
    const char* q_ = colML + ((mt) >> 1) * 2048 + (t) * 16384; \
    const unsigned x0_ = (unsigned)(((mt) & 1) << 4); \
    const unsigned w0_ = *(const unsigned*)(q_ +           0 + x0_); \
    const unsigned w1_ = *(const unsigned*)(q_ +         128 + (x0_ ^ 16u)); \
    const unsigned w2_ = *(const unsigned*)(q_ +         256 + x0_); \
    const unsigned w3_ = *(const unsigned*)(q_ +         384 + (x0_ ^ 16u)); \
    const unsigned w4_ = *(const unsigned*)(q_ + 8192 +    0 + x0_); \
    const unsigned w5_ = *(const unsigned*)(q_ + 8192 +  128 + (x0_ ^ 16u)); \
    const unsigned w6_ = *(const unsigned*)(q_ + 8192 +  256 + x0_); \
    const unsigned w7_ = *(const unsigned*)(q_ + 8192 +  384 + (x0_ ^ 16u)); \
    U8 M_ = {}, L_ = {}; \
    M_.u[0] = (w0_ & 0xffffu) | (w1_ << 16); \
    M_.u[1] = (w2_ & 0xffffu) | (w3_ << 16); \
    M_.u[2] = (w4_ & 0xffffu) | (w5_ << 16); \
    M_.u[3] = (w6_ & 0xffffu) | (w7_ << 16); \
    L_.u[0] = (w0_ >> 16) | (w1_ & 0xffff0000u); \
    L_.u[1] = (w2_ >> 16) | (w3_ & 0xffff0000u); \
    L_.u[2] = (w4_ >> 16) | (w5_ & 0xffff0000u); \
    L_.u[3] = (w6_ >> 16) | (w7_ & 0xffff0000u); \
    (Am) = M_.v; (Al) = L_.v; } while (0)

extern "C" __global__
__attribute__((amdgpu_flat_work_group_size(NTHREADS, NTHREADS), amdgpu_waves_per_eu(2, 2)))
void lnn_kernel(const float* __restrict__ gx, const float* __restrict__ gW1,
                const float* __restrict__ gb1, const float* __restrict__ gW2,
                const float* __restrict__ gb2, const float* __restrict__ gW3,
                float* __restrict__ gout)
{
    extern __shared__ __align__(16) char lds[];
    const int tid = threadIdx.x;

    // ---- purity hammer: LDS content = f(inputs) only, never prior-launch state
    for (int e4 = tid; e4 < (LDS_BYTES / 4); e4 += NTHREADS)
        ((unsigned*)lds)[e4] = 0u;
    __syncthreads();

    // ---- one-time: build W2 planes (exact software-RNE 3-split) ----
    for (int e = tid; e < 16384; e += NTHREADS) {
        const int r = e >> 7, c = e & 127;          // W2[r][c]
        const float w = gW2[e];
        const unsigned hb = bf16b(w);
        const float r1f = w - __uint_as_float(hb << 16);
        const unsigned mb = bf16b(r1f);
        const float r2f = r1f - __uint_as_float(mb << 16);
        const unsigned lb = bf16b(r2f);             // exact: w == h+m+l
        // fwd planes: A[m=r][k=c]; slot s=(r&15)*4+((c>>2)&3); elem e=((c>>4)&1)*4+(c&3)
        const int fragF = (r >> 4) * 4 + (c >> 5);
        const int sF    = (r & 15) * 4 + ((c >> 2) & 3);
        const int eF    = ((c >> 4) & 1) * 4 + (c & 3);
        *(unsigned short*)(lds + FWDH + fragF * 1024 + sF * 16 + eF * 2) = (unsigned short)hb;
        // ML pair-plane: 32B slots, half-swap XOR on (row&1) => conflict-free b128 reads
        *(unsigned*)(lds + FWDML + fragF * 2048 + sF * 32
                     + ((((eF >> 2) ^ ((sF >> 2) & 1)) << 4)) + (eF & 3) * 4)
            = mb | (lb << 16);
        // col-H plane: A'[m'=c][k'=r]
        const int fragC = (c >> 4) * 4 + (r >> 5);
        const int sC    = (c & 15) * 4 + ((r >> 2) & 3);
        const int eC    = ((r >> 4) & 1) * 4 + (r & 3);
        *(unsigned short*)(lds + COLH + fragC * 1024 + sC * 16 + eC * 2) = (unsigned short)hb;
    }
    __syncthreads();   // planes read-only from here; no further block syncs

    const int l  = tid & 63;
    const int wv = tid >> 6;
    const int n  = l & 15;        // row within wave tile
    const int gq = l >> 4;        // lane group (k-slice / channel sub-block)
    const int s  = n * 4 + gq;    // fragment lane-slot

    const char* aH    = lds + FWDH  + s * 16;
    const char* mlr0  = lds + FWDML + s * 32 + ((n & 1) << 4);        // elems 0-3
    const char* mlr1  = lds + FWDML + s * 32 + (((n & 1) ^ 1) << 4);  // elems 4-7
    const char* cH    = lds + COLH  + s * 16;
    const char* colML = lds + FWDML + gq * 512 + ((n >> 2) & 3) * 32 + (n & 3) * 4;

    const float4* gW14 = (const float4*)gW1;

#pragma unroll 1
    for (int it = 0; it < NITERS; ++it) {
        const int grow = blockIdx.x * (NITERS * 8 * 16) + wv * (NITERS * 16) + it * 16 + n;
        const float4 xr = ((const float4*)gx)[grow];

        // ---- P0: layer 1  p = softmax(W1 x + b1); pi2 = p.t2, pi3 = p.t3
        f32x4 p[8];
        float se = 0.f, s2a = 0.f, s3a = 0.f;
#pragma unroll
        for (int mt = 0; mt < 8; ++mt) {
#pragma unroll
            for (int j = 0; j < 4; ++j) {
                const int c = mt * 16 + gq * 4 + j;
                const float4 w1 = gW14[c];
                const float z1 = fmaf(w1.x, xr.x, fmaf(w1.y, xr.y,
                                  fmaf(w1.z, xr.z, fmaf(w1.w, xr.w, gb1[c]))));
                const float e1 = __expf(z1);
                p[mt][j] = e1;
                se += e1;
                s2a = fmaf(e1, w1.z, s2a);
                s3a = fmaf(e1, w1.w, s3a);
            }
        }
        se = red4(se); s2a = red4(s2a); s3a = red4(s3a);
        const float rs1 = 1.0f / se;
        const float pi2 = s2a * rs1, pi3 = s3a * rs1;
#pragma unroll
        for (int mt = 0; mt < 8; ++mt)
#pragma unroll
            for (int j = 0; j < 4; ++j) p[mt][j] *= rs1;

        // ---- Sweep 1: z = W2 p ; zd2 = W2 pd2 ; zd3 = W2 pd3
        f32x4 az[8] = {}, a2[8] = {}, a3[8] = {};
#pragma unroll
        for (int t = 0; t < 4; ++t) {
            float d2v[8], d3v[8];
#pragma unroll
            for (int u = 0; u < 2; ++u)
#pragma unroll
                for (int j = 0; j < 4; ++j) {
                    const int c = (2 * t + u) * 16 + gq * 4 + j;
                    const float4 w1 = gW14[c];
                    const float pc = p[2 * t + u][j];
                    d2v[u * 4 + j] = pc * (w1.z - pi2);
                    d3v[u * 4 + j] = pc * (w1.w - pi3);
                }
            bf16x8 Bph = {}, Bpm = {}, Bpl = {}; PACKB3(p, t, Bph, Bpm, Bpl);
            U8 H2_ = {}, M2_ = {}, L2_ = {}, H3_ = {}, M3_ = {}, L3_ = {};
            sp3(d2v[0], d2v[1], H2_.u[0], M2_.u[0], L2_.u[0]);
            sp3(d2v[2], d2v[3], H2_.u[1], M2_.u[1], L2_.u[1]);
            sp3(d2v[4], d2v[5], H2_.u[2], M2_.u[2], L2_.u[2]);
            sp3(d2v[6], d2v[7], H2_.u[3], M2_.u[3], L2_.u[3]);
            sp3(d3v[0], d3v[1], H3_.u[0], M3_.u[0], L3_.u[0]);
            sp3(d3v[2], d3v[3], H3_.u[1], M3_.u[1], L3_.u[1]);
            sp3(d3v[4], d3v[5], H3_.u[2], M3_.u[2], L3_.u[2]);
            sp3(d3v[6], d3v[7], H3_.u[3], M3_.u[3], L3_.u[3]);
            const bf16x8 B2h = H2_.v, B2m = M2_.v, B2l = L2_.v;
            const bf16x8 B3h = H3_.v, B3m = M3_.v, B3l = L3_.v;
#pragma unroll
            for (int mt = 0; mt < 8; ++mt) {
                bf16x8 Ah = {}, Am = {}, Al = {};
                LOADFWD(mt, t, Ah, Am, Al);
                PASS8(Ah, Am, Al, Bph, Bpm, Bpl, az[mt]);
                PASS8(Ah, Am, Al, B2h, B2m, B2l, a2[mt]);
                PASS8(Ah, Am, Al, B3h, B3m, B3l, a3[mt]);
            }
        }

        // ---- P3: softmax-2 chain; az->u, a2->ud2, a3->ud3 (in place)
        float s2 = 0.f, sw3 = 0.f, s2d2 = 0.f, s2d3 = 0.f, sw3d2 = 0.f, sw3d3 = 0.f;
#pragma unroll
        for (int mt = 0; mt < 8; ++mt)
#pragma unroll
            for (int j = 0; j < 4; ++j) {
                const int c = mt * 16 + gq * 4 + j;
                const float z  = az[mt][j] + gb2[c];
                const float e2 = __expf(z);
                const float w3c = gW3[c];
                az[mt][j] = e2;
                s2 += e2;
                sw3   = fmaf(w3c, e2, sw3);
                s2d2  = fmaf(e2, a2[mt][j], s2d2);
                s2d3  = fmaf(e2, a3[mt][j], s2d3);
                sw3d2 = fmaf(w3c * e2, a2[mt][j], sw3d2);
                sw3d3 = fmaf(w3c * e2, a3[mt][j], sw3d3);
            }
        s2 = red4(s2); sw3 = red4(sw3); s2d2 = red4(s2d2); s2d3 = red4(s2d3);
        sw3d2 = red4(sw3d2); sw3d3 = red4(sw3d3);
        const float rs2 = 1.0f / s2;
        const float sw  = sw3 * rs2;                       // W3.q
        const float sg2 = s2d2 * rs2, sg3 = s2d3 * rs2;    // q.zd_T
        const float sd2 = fmaf(-sg2, sw, sw3d2 * rs2);     // W3.qd2
        const float sd3 = fmaf(-sg3, sw, sw3d3 * rs2);
#pragma unroll
        for (int mt = 0; mt < 8; ++mt)
#pragma unroll
            for (int j = 0; j < 4; ++j) {
                const int c = mt * 16 + gq * 4 + j;
                const float w3c = gW3[c];
                const float e2 = az[mt][j];
                const float qq = e2 * rs2;
                const float uu = qq * (w3c - sw);
                const float zd2c = a2[mt][j], zd3c = a3[mt][j];
                az[mt][j] = uu;                                    // u
                a2[mt][j] = fmaf(uu, zd2c - sg2, -(sd2 * qq));     // ud2
                a3[mt][j] = fmaf(uu, zd3c - sg3, -(sd3 * qq));     // ud3
            }

        // ---- Sweep 2a: v = W2^T u
        f32x4 av[8] = {};
#pragma unroll
        for (int t = 0; t < 4; ++t) {
            bf16x8 Buh = {}, Bum = {}, Bul = {}; PACKB3(az, t, Buh, Bum, Bul);
#pragma unroll
            for (int mt = 0; mt < 8; ++mt) {
                bf16x8 Ah = {}, Am = {}, Al = {};
                LOADCOL(mt, t, Ah, Am, Al);
                PASS8(Ah, Am, Al, Buh, Bum, Bul, av[mt]);
            }
        }
        // ---- Sweep 2b: vd2 = W2^T ud2 ; vd3 = W2^T ud3
        f32x4 ad2[8] = {}, ad3[8] = {};
#pragma unroll
        for (int t = 0; t < 4; ++t) {
            bf16x8 B2h = {}, B2m = {}, B2l = {}; PACKB3(a2, t, B2h, B2m, B2l);
            bf16x8 B3h = {}, B3m = {}, B3l = {}; PACKB3(a3, t, B3h, B3m, B3l);
#pragma unroll
            for (int mt = 0; mt < 8; ++mt) {
                bf16x8 Ah = {}, Am = {}, Al = {};
                LOADCOL(mt, t, Ah, Am, Al);
                PASS8(Ah, Am, Al, B2h, B2m, B2l, ad2[mt]);
                PASS8(Ah, Am, Al, B3h, B3m, B3l, ad3[mt]);
            }
        }

        // ---- P5: recompute p (bit-identical); reductions; h's; fp64 solve
        f32x4 pr[8];
        float pv = 0.f, dv2 = 0.f, dv3 = 0.f;
#pragma unroll
        for (int mt = 0; mt < 8; ++mt)
#pragma unroll
            for (int j = 0; j < 4; ++j) {
                const int c = mt * 16 + gq * 4 + j;
                const float4 w1 = gW14[c];
                const float z1 = fmaf(w1.x, xr.x, fmaf(w1.y, xr.y,
                                  fmaf(w1.z, xr.z, fmaf(w1.w, xr.w, gb1[c]))));
                const float pc = __expf(z1) * rs1;
                pr[mt][j] = pc;
                const float pd2c = pc * (w1.z - pi2);
                const float pd3c = pc * (w1.w - pi3);
                pv  = fmaf(pc, av[mt][j], pv);
                dv2 = fmaf(pd2c, av[mt][j], fmaf(pc, ad2[mt][j], dv2));
                dv3 = fmaf(pd3c, av[mt][j], fmaf(pc, ad3[mt][j], dv3));
            }
        pv = red4(pv); dv2 = red4(dv2); dv3 = red4(dv3);

        float h20 = 0.f, h21 = 0.f, h22 = 0.f, h23 = 0.f;
        float h30 = 0.f, h31 = 0.f, h32 = 0.f, h33 = 0.f, g0a = 0.f;
#pragma unroll
        for (int mt = 0; mt < 8; ++mt)
#pragma unroll
            for (int j = 0; j < 4; ++j) {
                const int c = mt * 16 + gq * 4 + j;
                const float4 w1 = gW14[c];
                const float pc = pr[mt][j];
                const float pd2c = pc * (w1.z - pi2);
                const float pd3c = pc * (w1.w - pi3);
                const float vm = av[mt][j] - pv;
                const float gd2 = fmaf(pd2c, vm, pc * (ad2[mt][j] - dv2));
                const float gd3 = fmaf(pd3c, vm, pc * (ad3[mt][j] - dv3));
                h20 = fmaf(w1.x, gd2, h20); h21 = fmaf(w1.y, gd2, h21);
                h22 = fmaf(w1.z, gd2, h22); h23 = fmaf(w1.w, gd2, h23);
                h30 = fmaf(w1.x, gd3, h30); h31 = fmaf(w1.y, gd3, h31);
                h32 = fmaf(w1.z, gd3, h32); h33 = fmaf(w1.w, gd3, h33);
                g0a = fmaf(w1.x, pc * vm, g0a);
            }
        h20 = red4(h20); h21 = red4(h21); h22 = red4(h22); h23 = red4(h23);
        h30 = red4(h30); h31 = red4(h31); h32 = red4(h32); h33 = red4(h33);
        g0a = red4(g0a);

        // ---- 2x2 solve in fp64 (identical to R8)
        const double rhs0 = (double)g0a - ((double)h20 * (double)xr.z + (double)h21 * (double)xr.w);
        const double rhs1 = (double)g0a - ((double)h30 * (double)xr.z + (double)h31 * (double)xr.w);
        const double a_ = (double)h22, b_ = (double)h32, c_ = (double)h23, d_ = (double)h33;
        const double det = a_ * d_ - b_ * c_;
        const float t0 = (float)((d_ * rhs0 - b_ * rhs1) / det);
        const float t1 = (float)((a_ * rhs1 - c_ * rhs0) / det);
        if (gq == 0) {
            ((float4*)gout)[grow] = make_float4(xr.z, xr.w, t0, t1);
        }
    }
}

extern "C" void kernel_launch(void* const* d_in, const int* in_sizes, int n_in,
                              void* d_out, int out_size, void* d_ws, size_t ws_size,
                              hipStream_t stream)
{
    const float* gx  = (const float*)d_in[0];
    const float* gW1 = (const float*)d_in[1];
    const float* gb1 = (const float*)d_in[2];
    const float* gW2 = (const float*)d_in[3];
    const float* gb2 = (const float*)d_in[4];
    const float* gW3 = (const float*)d_in[5];
    float* gout = (float*)d_out;

    (void)hipFuncSetAttribute((const void*)lnn_kernel,
                              hipFuncAttributeMaxDynamicSharedMemorySize, LDS_BYTES);
    lnn_kernel<<<NGRID, NTHREADS, LDS_BYTES, stream>>>(gx, gW1, gb1, gW2, gb2, gW3, gout);
}

// Round 6
// 2359.251 us; speedup vs baseline: 1.0153x; 1.0104x over previous
//
#include <hip/hip_runtime.h>

// LNN R14: kill the scratch. R12/R13 evidence: VGPR=128 under BOTH occupancy
// declarations (launch_bounds(512,2) and waves_per_eu(2,2)) with identical
// 6GB FETCH+WRITE scratch traffic => not regalloc spill; data was allocated
// to scratch by construction. Suspect: U8 union type-punning (write .u[i],
// read .v) defeats SROA -> every PACKB3/LOADFWD/LOADCOL round-trips a 16B
// stack slot (~8.4 KB/thread/iter ~= the measured traffic; also explains the
// 23ms first-dispatch scratch-alloc anomaly).
// Fix: replace ALL unions with __builtin_bit_cast from a u32x4 vector --
// pure register bitcast, no memory. Bit-identical data movement => absmax
// must remain exactly 3584. Everything else unchanged from R12/R13:
// - LDS pre-zero purity hammer (fixed the launch-vs-graph tripwire).
// - Software-RNE bf16 3-split (exact), 8-pass split product (only ll dropped).
// - LDS 131072 B: fwd-H (32K) + fwd-ML pair plane (64K) + col-H (32K).
// - Wave = 16 rows; lane l owns row l&15, channels {16mt + 4(l>>4) + j}.

using bf16x8 = __attribute__((ext_vector_type(8))) short;
using f32x4  = __attribute__((ext_vector_type(4))) float;
using u32x4  = __attribute__((ext_vector_type(4))) unsigned;

#define NGRID    256
#define NTHREADS 512          // 8 waves; 16 rows/wave/iter
#define NITERS   8            // 256 * 8 * 16 * 8 = 262144 rows
#define FWDH  0
#define FWDML 32768
#define COLH  98304
#define LDS_BYTES 131072

__device__ __forceinline__ unsigned bf16b(float x) {           // RNE f32->bf16 bits
    unsigned u = __float_as_uint(x);
    return (u + 0x7fffu + ((u >> 16) & 1u)) >> 16;
}

// register-only pack of 4 dwords into a bf16x8 (NO union, NO memory)
__device__ __forceinline__ bf16x8 b8(unsigned a, unsigned b, unsigned c, unsigned d) {
    u32x4 t; t[0] = a; t[1] = b; t[2] = c; t[3] = d;
    return __builtin_bit_cast(bf16x8, t);
}

// exact 3-way bf16 split of a pair, packed (a in lo16, b in hi16 per level)
__device__ __forceinline__ void sp3(float a, float b, unsigned& h, unsigned& m, unsigned& l) {
    const unsigned ha = bf16b(a), hb = bf16b(b);
    h = ha | (hb << 16);
    const float ra = a - __uint_as_float(ha << 16);
    const float rb = b - __uint_as_float(hb << 16);
    const unsigned ma = bf16b(ra), mb = bf16b(rb);
    m = ma | (mb << 16);
    const float qa = ra - __uint_as_float(ma << 16);
    const float qb = rb - __uint_as_float(mb << 16);
    l = bf16b(qa) | (bf16b(qb) << 16);     // exact: residual fits 8 bits
}

__device__ __forceinline__ float red4(float x) {   // sum over the 4 lanes of one row
    x += __shfl_xor(x, 16, 64);
    x += __shfl_xor(x, 32, 64);
    return x;
}

#define MM(A, B, C) (C) = __builtin_amdgcn_mfma_f32_16x16x32_bf16((A), (B), (C), 0, 0, 0)
// 8-pass split product: only ll (~2^-32) dropped
#define PASS8(Ah, Am, Al, Bh, Bm, Bl, C) do { \
    MM(Ah, Bh, C); MM(Ah, Bm, C); MM(Am, Bh, C); MM(Am, Bm, C); \
    MM(Ah, Bl, C); MM(Al, Bh, C); MM(Am, Bl, C); MM(Al, Bm, C); } while (0)

// pack B-fragment (k-step t) from value array arr[8][4] (tiles 2t, 2t+1)
#define PACKB3(arr, t, Bh, Bm, Bl) do { \
    unsigned h0_,h1_,h2_,h3_,m0_,m1_,m2_,m3_,l0_,l1_,l2_,l3_; \
    sp3(arr[2*(t)][0],   arr[2*(t)][1],   h0_, m0_, l0_); \
    sp3(arr[2*(t)][2],   arr[2*(t)][3],   h1_, m1_, l1_); \
    sp3(arr[2*(t)+1][0], arr[2*(t)+1][1], h2_, m2_, l2_); \
    sp3(arr[2*(t)+1][2], arr[2*(t)+1][3], h3_, m3_, l3_); \
    (Bh) = b8(h0_, h1_, h2_, h3_); \
    (Bm) = b8(m0_, m1_, m2_, m3_); \
    (Bl) = b8(l0_, l1_, l2_, l3_); } while (0)

// fwd A-fragment: H via b128; M,L unpacked from the ML pair-plane (2x b128)
#define LOADFWD(mt, t, Ah, Am, Al) do { \
    const int fo_ = ((mt) * 4 + (t)); \
    (Ah) = *(const bf16x8*)(aH + fo_ * 1024); \
    const uint4 dA_ = *(const uint4*)(mlr0 + fo_ * 2048); /* elems 0-3 (m,l) pairs */ \
    const uint4 dB_ = *(const uint4*)(mlr1 + fo_ * 2048); /* elems 4-7 */ \
    (Am) = b8((dA_.x & 0xffffu) | (dA_.y << 16), (dA_.z & 0xffffu) | (dA_.w << 16), \
              (dB_.x & 0xffffu) | (dB_.y << 16), (dB_.z & 0xffffu) | (dB_.w << 16)); \
    (Al) = b8((dA_.x >> 16) | (dA_.y & 0xffff0000u), (dA_.z >> 16) | (dA_.w & 0xffff0000u), \
              (dB_.x >> 16) | (dB_.y & 0xffff0000u), (dB_.z >> 16) | (dB_.w & 0xffff0000u)); \
    } while (0)

// col (transpose) A-fragment: H via b128 from col-H plane; M,L gathered as
// 8x b32 from the fwd-ML plane (dword = m|l<<16 for W2[r][c2], r=32t+16u+4gq+j)
#define LOADCOL(mt, t, Ah, Am, Al) do { \
    (Ah) = *(const bf16x8*)(cH + ((mt) * 4 + (t)) * 1024); \
    const char* q_ = colML + ((mt) >> 1) * 2048 + (t) * 16384; \
    const unsigned x0_ = (unsigned)(((mt) & 1) << 4); \
    const unsigned w0_ = *(const unsigned*)(q_ +           0 + x0_); \
    const unsigned w1_ = *(const unsigned*)(q_ +         128 + (x0_ ^ 16u)); \
    const unsigned w2_ = *(const unsigned*)(q_ +         256 + x0_); \
    const unsigned w3_ = *(const unsigned*)(q_ +         384 + (x0_ ^ 16u)); \
    const unsigned w4_ = *(const unsigned*)(q_ + 8192 +    0 + x0_); \
    const unsigned w5_ = *(const unsigned*)(q_ + 8192 +  128 + (x0_ ^ 16u)); \
    const unsigned w6_ = *(const unsigned*)(q_ + 8192 +  256 + x0_); \
    const unsigned w7_ = *(const unsigned*)(q_ + 8192 +  384 + (x0_ ^ 16u)); \
    (Am) = b8((w0_ & 0xffffu) | (w1_ << 16), (w2_ & 0xffffu) | (w3_ << 16), \
              (w4_ & 0xffffu) | (w5_ << 16), (w6_ & 0xffffu) | (w7_ << 16)); \
    (Al) = b8((w0_ >> 16) | (w1_ & 0xffff0000u), (w2_ >> 16) | (w3_ & 0xffff0000u), \
              (w4_ >> 16) | (w5_ & 0xffff0000u), (w6_ >> 16) | (w7_ & 0xffff0000u)); \
    } while (0)

extern "C" __global__ __launch_bounds__(NTHREADS, 2)
void lnn_kernel(const float* __restrict__ gx, const float* __restrict__ gW1,
                const float* __restrict__ gb1, const float* __restrict__ gW2,
                const float* __restrict__ gb2, const float* __restrict__ gW3,
                float* __restrict__ gout)
{
    extern __shared__ __align__(16) char lds[];
    const int tid = threadIdx.x;

    // ---- purity hammer: LDS content = f(inputs) only, never prior-launch state
    for (int e4 = tid; e4 < (LDS_BYTES / 4); e4 += NTHREADS)
        ((unsigned*)lds)[e4] = 0u;
    __syncthreads();

    // ---- one-time: build W2 planes (exact software-RNE 3-split) ----
    for (int e = tid; e < 16384; e += NTHREADS) {
        const int r = e >> 7, c = e & 127;          // W2[r][c]
        const float w = gW2[e];
        const unsigned hb = bf16b(w);
        const float r1f = w - __uint_as_float(hb << 16);
        const unsigned mb = bf16b(r1f);
        const float r2f = r1f - __uint_as_float(mb << 16);
        const unsigned lb = bf16b(r2f);             // exact: w == h+m+l
        // fwd planes: A[m=r][k=c]; slot s=(r&15)*4+((c>>2)&3); elem e=((c>>4)&1)*4+(c&3)
        const int fragF = (r >> 4) * 4 + (c >> 5);
        const int sF    = (r & 15) * 4 + ((c >> 2) & 3);
        const int eF    = ((c >> 4) & 1) * 4 + (c & 3);
        *(unsigned short*)(lds + FWDH + fragF * 1024 + sF * 16 + eF * 2) = (unsigned short)hb;
        // ML pair-plane: 32B slots, half-swap XOR on (row&1) => conflict-free b128 reads
        *(unsigned*)(lds + FWDML + fragF * 2048 + sF * 32
                     + ((((eF >> 2) ^ ((sF >> 2) & 1)) << 4)) + (eF & 3) * 4)
            = mb | (lb << 16);
        // col-H plane: A'[m'=c][k'=r]
        const int fragC = (c >> 4) * 4 + (r >> 5);
        const int sC    = (c & 15) * 4 + ((r >> 2) & 3);
        const int eC    = ((r >> 4) & 1) * 4 + (r & 3);
        *(unsigned short*)(lds + COLH + fragC * 1024 + sC * 16 + eC * 2) = (unsigned short)hb;
    }
    __syncthreads();   // planes read-only from here; no further block syncs

    const int l  = tid & 63;
    const int wv = tid >> 6;
    const int n  = l & 15;        // row within wave tile
    const int gq = l >> 4;        // lane group (k-slice / channel sub-block)
    const int s  = n * 4 + gq;    // fragment lane-slot

    const char* aH    = lds + FWDH  + s * 16;
    const char* mlr0  = lds + FWDML + s * 32 + ((n & 1) << 4);        // elems 0-3
    const char* mlr1  = lds + FWDML + s * 32 + (((n & 1) ^ 1) << 4);  // elems 4-7
    const char* cH    = lds + COLH  + s * 16;
    const char* colML = lds + FWDML + gq * 512 + ((n >> 2) & 3) * 32 + (n & 3) * 4;

    const float4* gW14 = (const float4*)gW1;

#pragma unroll 1
    for (int it = 0; it < NITERS; ++it) {
        const int grow = blockIdx.x * (NITERS * 8 * 16) + wv * (NITERS * 16) + it * 16 + n;
        const float4 xr = ((const float4*)gx)[grow];

        // ---- P0: layer 1  p = softmax(W1 x + b1); pi2 = p.t2, pi3 = p.t3
        f32x4 p[8];
        float se = 0.f, s2a = 0.f, s3a = 0.f;
#pragma unroll
        for (int mt = 0; mt < 8; ++mt) {
#pragma unroll
            for (int j = 0; j < 4; ++j) {
                const int c = mt * 16 + gq * 4 + j;
                const float4 w1 = gW14[c];
                const float z1 = fmaf(w1.x, xr.x, fmaf(w1.y, xr.y,
                                  fmaf(w1.z, xr.z, fmaf(w1.w, xr.w, gb1[c]))));
                const float e1 = __expf(z1);
                p[mt][j] = e1;
                se += e1;
                s2a = fmaf(e1, w1.z, s2a);
                s3a = fmaf(e1, w1.w, s3a);
            }
        }
        se = red4(se); s2a = red4(s2a); s3a = red4(s3a);
        const float rs1 = 1.0f / se;
        const float pi2 = s2a * rs1, pi3 = s3a * rs1;
#pragma unroll
        for (int mt = 0; mt < 8; ++mt)
#pragma unroll
            for (int j = 0; j < 4; ++j) p[mt][j] *= rs1;

        // ---- Sweep 1: z = W2 p ; zd2 = W2 pd2 ; zd3 = W2 pd3
        f32x4 az[8] = {}, a2[8] = {}, a3[8] = {};
#pragma unroll
        for (int t = 0; t < 4; ++t) {
            float d2v[8], d3v[8];
#pragma unroll
            for (int u = 0; u < 2; ++u)
#pragma unroll
                for (int j = 0; j < 4; ++j) {
                    const int c = (2 * t + u) * 16 + gq * 4 + j;
                    const float4 w1 = gW14[c];
                    const float pc = p[2 * t + u][j];
                    d2v[u * 4 + j] = pc * (w1.z - pi2);
                    d3v[u * 4 + j] = pc * (w1.w - pi3);
                }
            bf16x8 Bph, Bpm, Bpl; PACKB3(p, t, Bph, Bpm, Bpl);
            unsigned h20_,h21_,h22_,h23_,m20_,m21_,m22_,m23_,l20_,l21_,l22_,l23_;
            unsigned h30_,h31_,h32_,h33_,m30_,m31_,m32_,m33_,l30_,l31_,l32_,l33_;
            sp3(d2v[0], d2v[1], h20_, m20_, l20_);
            sp3(d2v[2], d2v[3], h21_, m21_, l21_);
            sp3(d2v[4], d2v[5], h22_, m22_, l22_);
            sp3(d2v[6], d2v[7], h23_, m23_, l23_);
            sp3(d3v[0], d3v[1], h30_, m30_, l30_);
            sp3(d3v[2], d3v[3], h31_, m31_, l31_);
            sp3(d3v[4], d3v[5], h32_, m32_, l32_);
            sp3(d3v[6], d3v[7], h33_, m33_, l33_);
            const bf16x8 B2h = b8(h20_, h21_, h22_, h23_);
            const bf16x8 B2m = b8(m20_, m21_, m22_, m23_);
            const bf16x8 B2l = b8(l20_, l21_, l22_, l23_);
            const bf16x8 B3h = b8(h30_, h31_, h32_, h33_);
            const bf16x8 B3m = b8(m30_, m31_, m32_, m33_);
            const bf16x8 B3l = b8(l30_, l31_, l32_, l33_);
#pragma unroll
            for (int mt = 0; mt < 8; ++mt) {
                bf16x8 Ah, Am, Al;
                LOADFWD(mt, t, Ah, Am, Al);
                PASS8(Ah, Am, Al, Bph, Bpm, Bpl, az[mt]);
                PASS8(Ah, Am, Al, B2h, B2m, B2l, a2[mt]);
                PASS8(Ah, Am, Al, B3h, B3m, B3l, a3[mt]);
            }
        }

        // ---- P3: softmax-2 chain; az->u, a2->ud2, a3->ud3 (in place)
        float s2 = 0.f, sw3 = 0.f, s2d2 = 0.f, s2d3 = 0.f, sw3d2 = 0.f, sw3d3 = 0.f;
#pragma unroll
        for (int mt = 0; mt < 8; ++mt)
#pragma unroll
            for (int j = 0; j < 4; ++j) {
                const int c = mt * 16 + gq * 4 + j;
                const float z  = az[mt][j] + gb2[c];
                const float e2 = __expf(z);
                const float w3c = gW3[c];
                az[mt][j] = e2;
                s2 += e2;
                sw3   = fmaf(w3c, e2, sw3);
                s2d2  = fmaf(e2, a2[mt][j], s2d2);
                s2d3  = fmaf(e2, a3[mt][j], s2d3);
                sw3d2 = fmaf(w3c * e2, a2[mt][j], sw3d2);
                sw3d3 = fmaf(w3c * e2, a3[mt][j], sw3d3);
            }
        s2 = red4(s2); sw3 = red4(sw3); s2d2 = red4(s2d2); s2d3 = red4(s2d3);
        sw3d2 = red4(sw3d2); sw3d3 = red4(sw3d3);
        const float rs2 = 1.0f / s2;
        const float sw  = sw3 * rs2;                       // W3.q
        const float sg2 = s2d2 * rs2, sg3 = s2d3 * rs2;    // q.zd_T
        const float sd2 = fmaf(-sg2, sw, sw3d2 * rs2);     // W3.qd2
        const float sd3 = fmaf(-sg3, sw, sw3d3 * rs2);
#pragma unroll
        for (int mt = 0; mt < 8; ++mt)
#pragma unroll
            for (int j = 0; j < 4; ++j) {
                const int c = mt * 16 + gq * 4 + j;
                const float w3c = gW3[c];
                const float e2 = az[mt][j];
                const float qq = e2 * rs2;
                const float uu = qq * (w3c - sw);
                const float zd2c = a2[mt][j], zd3c = a3[mt][j];
                az[mt][j] = uu;                                    // u
                a2[mt][j] = fmaf(uu, zd2c - sg2, -(sd2 * qq));     // ud2
                a3[mt][j] = fmaf(uu, zd3c - sg3, -(sd3 * qq));     // ud3
            }

        // ---- Sweep 2a: v = W2^T u
        f32x4 av[8] = {};
#pragma unroll
        for (int t = 0; t < 4; ++t) {
            bf16x8 Buh, Bum, Bul; PACKB3(az, t, Buh, Bum, Bul);
#pragma unroll
            for (int mt = 0; mt < 8; ++mt) {
                bf16x8 Ah, Am, Al;
                LOADCOL(mt, t, Ah, Am, Al);
                PASS8(Ah, Am, Al, Buh, Bum, Bul, av[mt]);
            }
        }
        // ---- Sweep 2b: vd2 = W2^T ud2 ; vd3 = W2^T ud3
        f32x4 ad2[8] = {}, ad3[8] = {};
#pragma unroll
        for (int t = 0; t < 4; ++t) {
            bf16x8 B2h, B2m, B2l; PACKB3(a2, t, B2h, B2m, B2l);
            bf16x8 B3h, B3m, B3l; PACKB3(a3, t, B3h, B3m, B3l);
#pragma unroll
            for (int mt = 0; mt < 8; ++mt) {
                bf16x8 Ah, Am, Al;
                LOADCOL(mt, t, Ah, Am, Al);
                PASS8(Ah, Am, Al, B2h, B2m, B2l, ad2[mt]);
                PASS8(Ah, Am, Al, B3h, B3m, B3l, ad3[mt]);
            }
        }

        // ---- P5: recompute p (bit-identical); reductions; h's; fp64 solve
        f32x4 pr[8];
        float pv = 0.f, dv2 = 0.f, dv3 = 0.f;
#pragma unroll
        for (int mt = 0; mt < 8; ++mt)
#pragma unroll
            for (int j = 0; j < 4; ++j) {
                const int c = mt * 16 + gq * 4 + j;
                const float4 w1 = gW14[c];
                const float z1 = fmaf(w1.x, xr.x, fmaf(w1.y, xr.y,
                                  fmaf(w1.z, xr.z, fmaf(w1.w, xr.w, gb1[c]))));
                const float pc = __expf(z1) * rs1;
                pr[mt][j] = pc;
                const float pd2c = pc * (w1.z - pi2);
                const float pd3c = pc * (w1.w - pi3);
                pv  = fmaf(pc, av[mt][j], pv);
                dv2 = fmaf(pd2c, av[mt][j], fmaf(pc, ad2[mt][j], dv2));
                dv3 = fmaf(pd3c, av[mt][j], fmaf(pc, ad3[mt][j], dv3));
            }
        pv = red4(pv); dv2 = red4(dv2); dv3 = red4(dv3);

        float h20 = 0.f, h21 = 0.f, h22 = 0.f, h23 = 0.f;
        float h30 = 0.f, h31 = 0.f, h32 = 0.f, h33 = 0.f, g0a = 0.f;
#pragma unroll
        for (int mt = 0; mt < 8; ++mt)
#pragma unroll
            for (int j = 0; j < 4; ++j) {
                const int c = mt * 16 + gq * 4 + j;
                const float4 w1 = gW14[c];
                const float pc = pr[mt][j];
                const float pd2c = pc * (w1.z - pi2);
                const float pd3c = pc * (w1.w - pi3);
                const float vm = av[mt][j] - pv;
                const float gd2 = fmaf(pd2c, vm, pc * (ad2[mt][j] - dv2));
                const float gd3 = fmaf(pd3c, vm, pc * (ad3[mt][j] - dv3));
                h20 = fmaf(w1.x, gd2, h20); h21 = fmaf(w1.y, gd2, h21);
                h22 = fmaf(w1.z, gd2, h22); h23 = fmaf(w1.w, gd2, h23);
                h30 = fmaf(w1.x, gd3, h30); h31 = fmaf(w1.y, gd3, h31);
                h32 = fmaf(w1.z, gd3, h32); h33 = fmaf(w1.w, gd3, h33);
                g0a = fmaf(w1.x, pc * vm, g0a);
            }
        h20 = red4(h20); h21 = red4(h21); h22 = red4(h22); h23 = red4(h23);
        h30 = red4(h30); h31 = red4(h31); h32 = red4(h32); h33 = red4(h33);
        g0a = red4(g0a);

        // ---- 2x2 solve in fp64 (identical to R8)
        const double rhs0 = (double)g0a - ((double)h20 * (double)xr.z + (double)h21 * (double)xr.w);
        const double rhs1 = (double)g0a - ((double)h30 * (double)xr.z + (double)h31 * (double)xr.w);
        const double a_ = (double)h22, b_ = (double)h32, c_ = (double)h23, d_ = (double)h33;
        const double det = a_ * d_ - b_ * c_;
        const float t0 = (float)((d_ * rhs0 - b_ * rhs1) / det);
        const float t1 = (float)((a_ * rhs1 - c_ * rhs0) / det);
        if (gq == 0) {
            ((float4*)gout)[grow] = make_float4(xr.z, xr.w, t0, t1);
        }
    }
}

extern "C" void kernel_launch(void* const* d_in, const int* in_sizes, int n_in,
                              void* d_out, int out_size, void* d_ws, size_t ws_size,
                              hipStream_t stream)
{
    const float* gx  = (const float*)d_in[0];
    const float* gW1 = (const float*)d_in[1];
    const float* gb1 = (const float*)d_in[2];
    const float* gW2 = (const float*)d_in[3];
    const float* gb2 = (const float*)d_in[4];
    const float* gW3 = (const float*)d_in[5];
    float* gout = (float*)d_out;

    (void)hipFuncSetAttribute((const void*)lnn_kernel,
                              hipFuncAttributeMaxDynamicSharedMemorySize, LDS_BYTES);
    lnn_kernel<<<NGRID, NTHREADS, LDS_BYTES, stream>>>(gx, gW1, gb1, gW2, gb2, gW3, gout);
}